// Round 4
// baseline (198.049 us; speedup 1.0000x reference)
//
#include <hip/hip_runtime.h>
#include <math.h>

// ---------------------------------------------------------------------------
// FrameDockingScoreModel — round 12.
//
// r11 falsified the "per-wave input MLP" theory: per-item VALU restored to
// r8's 1,481 inst (VALU busy-time 18.8 us), waves halved, loads up front —
// wall unchanged at 50 us, VALUBusy 37%. The per-item-INVARIANT cost is the
// scalar weight stream: ~755 dwords (3 KB) of ws re-read through K$ per
// ITEM (~11.8 MB/CU against the wall), lgkmcnt-correlated across waves.
// r8's own history supports SMEM as first-order: removing s_load fences
// (91->51 us) was the only prior structural win.
//
// Round-12: halve SMEM traffic with ZERO VALU inflation. Dual adjacent
// items per thread, INTERLEAVED scalar-fmaf matvec: one 36-dword s_load
// group feeds 72 FMAs (A row, then B row; per-item chain order identical
// to r8 -> bitwise-identical results).
//  - r10's ItemState + epilogue hoist (32 live floats/item, WRITE-clean
//    proven) kills r9's spill mode.
//  - r8's row-major ws + scalar fmaf + uniform-load s_load codegen kills
//    r10's pk-fma/v2f VALU-inflation mode.
//  - __launch_bounds__(256,4): VGPR cap 128 (need ~85), no forced spill.
// Checks: WRITE_SIZE == 46875 KB exactly; VALU busy-time ~19-20 us total.
// Predicted fd12: 30-42 us, VALUBusy 50-65%. Falsifier: ~50 us @ 37% ->
// SMEM theory dead, next round LDS-broadcast cross-check.
// ---------------------------------------------------------------------------

#define K_A   (0.10846522890932808f * 0.24253562503633297f)  // C2_000*C1_000
#define K_B   (0.10846522890932808f * 0.14002800840979312f)  // C2_000*C1_110
#define K_P   (0.06262242910851495f * 0.33333333333333333f)  // C2_110*C1_011
#define K_Q   (0.06262242910851495f * 0.33333333333333333f)  // C2_110*C1_101
#define K_R   (0.06262242910851495f * 0.23570226039551584f)  // C2_110*C1_111
#define K_WB  (0.14907119849998599f * 0.24253562503633297f)  // C2_011*C1_000
#define K_CB  (0.14907119849998599f * 0.14002800840979312f)  // C2_011*C1_110
#define K_WA  (0.14907119849998599f * 0.33333333333333333f)  // C2_101*C1_011
#define K_WBT (0.14907119849998599f * 0.33333333333333333f)  // C2_101*C1_101
#define K_WC  (0.14907119849998599f * 0.23570226039551584f)  // C2_101*C1_111
#define K_WA3 (0.10540925533894598f * 0.33333333333333333f)  // C2_111*C1_011
#define K_WB3 (0.10540925533894598f * 0.33333333333333333f)  // C2_111*C1_101
#define K_WC3 (0.10540925533894598f * 0.23570226039551584f)  // C2_111*C1_111

// ws layout: 80 rows x 9 floats (rows 77..79 zero) = 720, then extras
#define EX_WB   720   // 16
#define EX_CB   736   // 1 (737..739 pad)
#define EX_WA   740   // 16
#define EX_WBT  756   // 16
#define EX_WC   772   // 4
#define EX_WA3  776   // 4
#define EX_WB3  780   // 4
#define EX_WC3  784   // 1
#define N_WS    785

__global__ void fd12_prep(const float* __restrict__ w1_000, const float* __restrict__ w1_110,
                          const float* __restrict__ w1_011, const float* __restrict__ w1_101,
                          const float* __restrict__ w1_111, const float* __restrict__ w2_000,
                          const float* __restrict__ w2_110, const float* __restrict__ w2_011,
                          const float* __restrict__ w2_101, const float* __restrict__ w2_111,
                          float* __restrict__ ws)
{
    int j = blockIdx.x * 256 + threadIdx.x;
    if (j >= N_WS) return;
    float val = 0.f;
    if (j < 720) {
        int r = j / 9, c = j - r * 9;
        if (r < 64) {                       // s1(x)s2(x)s3 rows
            int pq = r >> 2, v = r & 3;
            float a = 0.f;
            for (int u = 0; u < 20; ++u)
                a = fmaf(w1_000[pq * 20 + u], w2_000[u * 36 + v * 9 + c], a);
            val = K_A * a;
        } else if (r < 68) {                // dot12*s3 rows
            int v = r - 64; float a = 0.f;
            for (int u = 0; u < 20; ++u)
                a = fmaf(w1_110[u], w2_000[u * 36 + v * 9 + c], a);
            val = K_B * a;
        } else if (r < 72) {                // d23*s1 rows
            int u = r - 68; float a = 0.f;
            for (int m = 0; m < 5; ++m)
                a = fmaf(w1_011[u * 5 + m], w2_110[m * 9 + c], a);
            val = K_P * a;
        } else if (r < 76) {                // d13*s2 rows
            int u = r - 72; float a = 0.f;
            for (int m = 0; m < 5; ++m)
                a = fmaf(w1_101[u * 5 + m], w2_110[m * 9 + c], a);
            val = K_Q * a;
        } else if (r == 76) {               // dtp row
            float a = 0.f;
            for (int m = 0; m < 5; ++m)
                a = fmaf(w1_111[m], w2_110[m * 9 + c], a);
            val = K_R * a;
        }                                   // rows 77..79: zero
    } else {
        int k = j - 720;
        if (k < 16) {                       // WB[pq]
            float a = 0.f;
            for (int u = 0; u < 20; ++u)
                a = fmaf(w2_011[u], w1_000[k * 20 + u], a);
            val = K_WB * a;
        } else if (k == 16) {               // CB
            float a = 0.f;
            for (int u = 0; u < 20; ++u)
                a = fmaf(w2_011[u], w1_110[u], a);
            val = K_CB * a;
        } else if (k >= 20 && k < 36) {     // WA[u*4+v]
            int u = (k - 20) >> 2, v = (k - 20) & 3;
            float a = 0.f;
            for (int m = 0; m < 5; ++m)
                a = fmaf(w1_011[u * 5 + m], w2_101[m * 4 + v], a);
            val = K_WA * a;
        } else if (k >= 36 && k < 52) {     // WBT[u*4+v]
            int u = (k - 36) >> 2, v = (k - 36) & 3;
            float a = 0.f;
            for (int m = 0; m < 5; ++m)
                a = fmaf(w1_101[u * 5 + m], w2_101[m * 4 + v], a);
            val = K_WBT * a;
        } else if (k >= 52 && k < 56) {     // WC[v]
            int v = k - 52; float a = 0.f;
            for (int m = 0; m < 5; ++m)
                a = fmaf(w1_111[m], w2_101[m * 4 + v], a);
            val = K_WC * a;
        } else if (k >= 56 && k < 60) {     // WA3[u]
            int u = k - 56; float a = 0.f;
            for (int m = 0; m < 5; ++m)
                a = fmaf(w2_111[m], w1_011[u * 5 + m], a);
            val = K_WA3 * a;
        } else if (k >= 60 && k < 64) {     // WB3[v]
            int v = k - 60; float a = 0.f;
            for (int m = 0; m < 5; ++m)
                a = fmaf(w2_111[m], w1_101[v * 5 + m], a);
            val = K_WB3 * a;
        } else if (k == 64) {               // WC3
            float a = 0.f;
            for (int m = 0; m < 5; ++m)
                a = fmaf(w2_111[m], w1_111[m], a);
            val = K_WC3 * a;
        }
    }
    ws[j] = val;
}

// Per-item state kept live through the matvec: 32 floats (r10-proven).
struct ItemState {
    float s1[4], s2[4], s3[4];
    float dot12, d13, d23, dtp;
    float v3x, v3y, v3z;
    float px, py, pz;     // epilogue-hoisted V2 partial (all but the sg*v3 term)
};

__device__ __forceinline__ ItemState geom(const float4 l0, const float4 l1, const float4 l2,
                                          const float4 r0, const float4 r1, const float4 r2,
                                          const float* __restrict__ ws)
{
    ItemState st;
    float e1x = l0.w - r0.w, e1y = l1.x - r1.x, e1z = l1.y - r1.y;
    float e2x = l1.z - r1.z, e2y = l1.w - r1.w, e2z = l2.x - r2.x;
    float e3x = l2.y - r2.y, e3y = l2.z - r2.z, e3z = l2.w - r2.w;

    float n1 = fmaf(e1x, e1x, fmaf(e1y, e1y, e1z * e1z));
    float n2 = fmaf(e2x, e2x, fmaf(e2y, e2y, e2z * e2z));
    float n3q = fmaf(e3x, e3x, fmaf(e3y, e3y, e3z * e3z));
    float i1 = __builtin_amdgcn_rsqf(n1);
    float i2 = __builtin_amdgcn_rsqf(n2);
    float i3 = __builtin_amdgcn_rsqf(n3q);
    float d1 = n1 * i1, d2 = n2 * i2, d3 = n3q * i3;

    float v1x = e1x * i1, v1y = e1y * i1, v1z = e1z * i1;
    float v2x = e2x * i2, v2y = e2y * i2, v2z = e2z * i2;
    st.v3x = e3x * i3; st.v3y = e3y * i3; st.v3z = e3z * i3;

    const float coeff = -0.18f;
    const float o1 = 1.6666666f, o2 = 3.3333333f, o3 = 5.f;
    float x;
    x = d1;      st.s1[0] = __expf(coeff * x * x);
    x = d1 - o1; st.s1[1] = __expf(coeff * x * x);
    x = d1 - o2; st.s1[2] = __expf(coeff * x * x);
    x = d1 - o3; st.s1[3] = __expf(coeff * x * x);
    x = d2;      st.s2[0] = __expf(coeff * x * x);
    x = d2 - o1; st.s2[1] = __expf(coeff * x * x);
    x = d2 - o2; st.s2[2] = __expf(coeff * x * x);
    x = d2 - o3; st.s2[3] = __expf(coeff * x * x);
    x = d3;      st.s3[0] = __expf(coeff * x * x);
    x = d3 - o1; st.s3[1] = __expf(coeff * x * x);
    x = d3 - o2; st.s3[2] = __expf(coeff * x * x);
    x = d3 - o3; st.s3[3] = __expf(coeff * x * x);

    st.dot12 = v1x * v2x + v1y * v2y + v1z * v2z;
    st.d13   = v1x * st.v3x + v1y * st.v3y + v1z * st.v3z;
    st.d23   = v2x * st.v3x + v2y * st.v3y + v2z * st.v3z;
    float c12x = v1y * v2z - v1z * v2y;
    float c12y = v1z * v2x - v1x * v2z;
    float c12z = v1x * v2y - v1y * v2x;
    st.dtp = c12x * st.v3x + c12y * st.v3y + c12z * st.v3z;

    // ---- epilogue scalars (depend only on s1/s2/s3 + ws extras) ----
    float ta = 0.f, tb = 0.f;
#pragma unroll
    for (int u = 0; u < 4; ++u) {
        float da = fmaf(ws[EX_WA + u * 4 + 0], st.s3[0], fmaf(ws[EX_WA + u * 4 + 1], st.s3[1],
                   fmaf(ws[EX_WA + u * 4 + 2], st.s3[2], ws[EX_WA + u * 4 + 3] * st.s3[3])));
        float db = fmaf(ws[EX_WBT + u * 4 + 0], st.s3[0], fmaf(ws[EX_WBT + u * 4 + 1], st.s3[1],
                   fmaf(ws[EX_WBT + u * 4 + 2], st.s3[2], ws[EX_WBT + u * 4 + 3] * st.s3[3])));
        ta = fmaf(st.s1[u], da, ta);
        tb = fmaf(st.s2[u], db, tb);
    }
    float tc = fmaf(ws[EX_WC + 0], st.s3[0], fmaf(ws[EX_WC + 1], st.s3[1],
               fmaf(ws[EX_WC + 2], st.s3[2], ws[EX_WC + 3] * st.s3[3])));
    float wa = fmaf(ws[EX_WA3 + 0], st.s1[0], fmaf(ws[EX_WA3 + 1], st.s1[1],
               fmaf(ws[EX_WA3 + 2], st.s1[2], ws[EX_WA3 + 3] * st.s1[3])));
    float wb = fmaf(ws[EX_WB3 + 0], st.s2[0], fmaf(ws[EX_WB3 + 1], st.s2[1],
               fmaf(ws[EX_WB3 + 2], st.s2[2], ws[EX_WB3 + 3] * st.s2[3])));
    float wc = ws[EX_WC3];

    float c23x = v2y * st.v3z - v2z * st.v3y;
    float c23y = v2z * st.v3x - v2x * st.v3z;
    float c23z = v2x * st.v3y - v2y * st.v3x;
    float c13x = v1y * st.v3z - v1z * st.v3y;
    float c13y = v1z * st.v3x - v1x * st.v3z;
    float c13z = v1x * st.v3y - v1y * st.v3x;
    float ccrx = c12y * st.v3z - c12z * st.v3y;
    float ccry = c12z * st.v3x - c12x * st.v3z;
    float ccrz = c12x * st.v3y - c12y * st.v3x;

    st.px = ta * v2x + tb * v1x + tc * c12x + wa * c23x + wb * c13x + wc * ccrx;
    st.py = ta * v2y + tb * v1y + tc * c12y + wa * c23y + wb * c13y + wc * ccry;
    st.pz = ta * v2z + tb * v1z + tc * c12z + wa * c23z + wb * c13z + wc * ccrz;
    return st;
}

__global__ __launch_bounds__(256, 4) void
fd12(const float* __restrict__ lig, const float* __restrict__ rec,
     const float* __restrict__ ws, float* __restrict__ out, int n)
{
    const int t = blockIdx.x * 256 + threadIdx.x;
    const size_t iA = (size_t)t * 2;
    if (iA >= (size_t)n) return;
    const bool two = (iA + 1) < (size_t)n;
    const size_t iB = two ? iA + 1 : iA;    // tail: duplicate A (stores guarded)

    // 12 dwordx4 issued upfront
    const float4* LA = (const float4*)(lig + iA * 12);
    const float4* RA = (const float4*)(rec + iA * 12);
    const float4* LB = (const float4*)(lig + iB * 12);
    const float4* RB = (const float4*)(rec + iB * 12);
    float4 lA0 = LA[0], lA1 = LA[1], lA2 = LA[2];
    float4 rA0 = RA[0], rA1 = RA[1], rA2 = RA[2];
    float4 lB0 = LB[0], lB1 = LB[1], lB2 = LB[2];
    float4 rB0 = RB[0], rB1 = RB[1], rB2 = RB[2];

    // Phase-pinned: geom A | geom B | interleaved matvec.
    ItemState A = geom(lA0, lA1, lA2, rA0, rA1, rA2, ws);
    __builtin_amdgcn_sched_barrier(0);
    ItemState B = geom(lB0, lB1, lB2, rB0, rB1, rB2, ws);
    __builtin_amdgcn_sched_barrier(0);

    // ------------- 77-row matvec, dual items, ONE s_load stream -----------
    // Scalar fmaf only (r8 codegen); each 36-dword group feeds 72 FMAs.
    // Per-item chain order identical to r8 -> bitwise-identical results.
    float accA0 = 0.f, accA1 = 0.f, accA2 = 0.f, accA3 = 0.f, accA4 = 0.f;
    float accA5 = 0.f, accA6 = 0.f, accA7 = 0.f, accA8 = 0.f;
    float accB0 = 0.f, accB1 = 0.f, accB2 = 0.f, accB3 = 0.f, accB4 = 0.f;
    float accB5 = 0.f, accB6 = 0.f, accB7 = 0.f, accB8 = 0.f;

#define ROW9D(wp_, off_, xa_, xb_) do { \
    accA0 = fmaf(xa_, wp_[off_ + 0], accA0); accA1 = fmaf(xa_, wp_[off_ + 1], accA1); \
    accA2 = fmaf(xa_, wp_[off_ + 2], accA2); accA3 = fmaf(xa_, wp_[off_ + 3], accA3); \
    accA4 = fmaf(xa_, wp_[off_ + 4], accA4); accA5 = fmaf(xa_, wp_[off_ + 5], accA5); \
    accA6 = fmaf(xa_, wp_[off_ + 6], accA6); accA7 = fmaf(xa_, wp_[off_ + 7], accA7); \
    accA8 = fmaf(xa_, wp_[off_ + 8], accA8); \
    accB0 = fmaf(xb_, wp_[off_ + 0], accB0); accB1 = fmaf(xb_, wp_[off_ + 1], accB1); \
    accB2 = fmaf(xb_, wp_[off_ + 2], accB2); accB3 = fmaf(xb_, wp_[off_ + 3], accB3); \
    accB4 = fmaf(xb_, wp_[off_ + 4], accB4); accB5 = fmaf(xb_, wp_[off_ + 5], accB5); \
    accB6 = fmaf(xb_, wp_[off_ + 6], accB6); accB7 = fmaf(xb_, wp_[off_ + 7], accB7); \
    accB8 = fmaf(xb_, wp_[off_ + 8], accB8); \
} while (0)

#define GROUP4D(g, xa0, xa1, xa2, xa3, xb0, xb1, xb2, xb3) do { \
    const float* wp_ = ws + 36 * (g); \
    const float a0_ = (xa0), a1_ = (xa1), a2_ = (xa2), a3_ = (xa3); \
    const float b0_ = (xb0), b1_ = (xb1), b2_ = (xb2), b3_ = (xb3); \
    ROW9D(wp_,  0, a0_, b0_); \
    ROW9D(wp_,  9, a1_, b1_); \
    ROW9D(wp_, 18, a2_, b2_); \
    ROW9D(wp_, 27, a3_, b3_); \
} while (0)

    const float cb = ws[EX_CB];
    float sgA = A.dot12 * cb, sgB = B.dot12 * cb;

#pragma unroll
    for (int p = 0; p < 4; ++p) {
#pragma unroll
        for (int q = 0; q < 4; ++q) {
            const int pq = p * 4 + q;
            const float oA = A.s1[p] * A.s2[q];
            const float oB = B.s1[p] * B.s2[q];
            const float wbq = ws[EX_WB + pq];
            sgA = fmaf(oA, wbq, sgA);
            sgB = fmaf(oB, wbq, sgB);
            GROUP4D(pq, oA * A.s3[0], oA * A.s3[1], oA * A.s3[2], oA * A.s3[3],
                        oB * B.s3[0], oB * B.s3[1], oB * B.s3[2], oB * B.s3[3]);
        }
    }
    GROUP4D(16, A.dot12 * A.s3[0], A.dot12 * A.s3[1], A.dot12 * A.s3[2], A.dot12 * A.s3[3],
                B.dot12 * B.s3[0], B.dot12 * B.s3[1], B.dot12 * B.s3[2], B.dot12 * B.s3[3]);
    GROUP4D(17, A.d23 * A.s1[0], A.d23 * A.s1[1], A.d23 * A.s1[2], A.d23 * A.s1[3],
                B.d23 * B.s1[0], B.d23 * B.s1[1], B.d23 * B.s1[2], B.d23 * B.s1[3]);
    GROUP4D(18, A.d13 * A.s2[0], A.d13 * A.s2[1], A.d13 * A.s2[2], A.d13 * A.s2[3],
                B.d13 * B.s2[0], B.d13 * B.s2[1], B.d13 * B.s2[2], B.d13 * B.s2[3]);
    {   // group 19: row 76 only (rows 77..79 zero)
        const float* wp = ws + 36 * 19;
        ROW9D(wp, 0, A.dtp, B.dtp);
    }
#undef GROUP4D
#undef ROW9D

    // ---------------- finish V2 = sg*v3 + P ----------------
    float V2xA = fmaf(sgA, A.v3x, A.px);
    float V2yA = fmaf(sgA, A.v3y, A.py);
    float V2zA = fmaf(sgA, A.v3z, A.pz);
    float V2xB = fmaf(sgB, B.v3x, B.px);
    float V2yB = fmaf(sgB, B.v3y, B.py);
    float V2zB = fmaf(sgB, B.v3z, B.pz);

    // ---------------- stores: 12x dwordx2 (pair outputs contiguous) -------
    const size_t n3 = (size_t)n * 3;
    const size_t base = iA * 3;             // 8B-aligned (iA even)
    if (two) {
        *(float2*)(out + base + 0)          = make_float2(accA0, accA1);
        *(float2*)(out + base + 2)          = make_float2(accA2, accB0);
        *(float2*)(out + base + 4)          = make_float2(accB1, accB2);
        *(float2*)(out + n3 + base + 0)     = make_float2(accA3, accA4);
        *(float2*)(out + n3 + base + 2)     = make_float2(accA5, accB3);
        *(float2*)(out + n3 + base + 4)     = make_float2(accB4, accB5);
        *(float2*)(out + 2 * n3 + base + 0) = make_float2(accA6, accA7);
        *(float2*)(out + 2 * n3 + base + 2) = make_float2(accA8, accB6);
        *(float2*)(out + 2 * n3 + base + 4) = make_float2(accB7, accB8);
        *(float2*)(out + 3 * n3 + base + 0) = make_float2(V2xA, V2yA);
        *(float2*)(out + 3 * n3 + base + 2) = make_float2(V2zA, V2xB);
        *(float2*)(out + 3 * n3 + base + 4) = make_float2(V2yB, V2zB);
    } else {                                // odd-n tail: item A only
        out[base + 0] = accA0;
        out[base + 1] = accA1;
        out[base + 2] = accA2;
        out[n3 + base + 0] = accA3;
        out[n3 + base + 1] = accA4;
        out[n3 + base + 2] = accA5;
        out[2 * n3 + base + 0] = accA6;
        out[2 * n3 + base + 1] = accA7;
        out[2 * n3 + base + 2] = accA8;
        out[3 * n3 + base + 0] = V2xA;
        out[3 * n3 + base + 1] = V2yA;
        out[3 * n3 + base + 2] = V2zA;
    }
}

extern "C" void kernel_launch(void* const* d_in, const int* in_sizes, int n_in,
                              void* d_out, int out_size, void* d_ws, size_t ws_size,
                              hipStream_t stream) {
    const float* lig = (const float*)d_in[0];
    const float* rec = (const float*)d_in[1];
    float* ws = (float*)d_ws;

    fd12_prep<<<4, 256, 0, stream>>>(
        (const float*)d_in[2], (const float*)d_in[3], (const float*)d_in[4],
        (const float*)d_in[5], (const float*)d_in[6], (const float*)d_in[7],
        (const float*)d_in[8], (const float*)d_in[9], (const float*)d_in[10],
        (const float*)d_in[11], ws);

    int n = in_sizes[0] / 12;
    int nPairs = (n + 1) / 2;
    int blocks = (nPairs + 255) / 256;
    fd12<<<blocks, 256, 0, stream>>>(lig, rec, ws, (float*)d_out, n);
}

// Round 5
// 156.286 us; speedup vs baseline: 1.2672x; 1.2672x over previous
//
#include <hip/hip_runtime.h>
#include <math.h>

// ---------------------------------------------------------------------------
// FrameDockingScoreModel — round 13.
//
// r12 post-mortem: launch_bounds(256,4) made the allocator target 64 VGPR and
// scratch-spill (+24MB WRITE, +70MB FETCH). Confounded. Also the r12 SMEM
// arithmetic was wrong by 64x: weights are wave-uniform, so the s_load
// stream is per WAVE (~3KB) -> ~1.5 B/cycle/CU. SMEM throughput is dead.
//
// Clean r8/r11 evidence: wall (50us) and VALUBusy (37%) invariant to wave
// count, per-wave MLP, and items/thread. Remaining shared, per-item-invariant
// suspect: INSTRUCTION FETCH. r8 body = ~1700 straight-line inst ~= 13KB;
// 4 blocks/CU at staggered PCs = ~50KB I$ working set vs 32KB L1I ->
// correlated fetch stalls. r11 doubled code AND items -> bytes/item constant
// -> same wall (the invariant r11 preserved).
//
// Round-13: r8 single-item body, bitwise-identical numerics, but the 16
// pq-groups become a "#pragma unroll 1" loop over p (q unrolled inside):
// matvec 16x45 -> ~180 inst. No arrays / no dynamic indexing (scratch rule):
// s1 via explicit register rotation, s2/s3 as named scalars. Tail groups
// 16-19 straight-line as in r8. Kernel ~6KB -> 4-block I$ set ~24KB < 32KB.
// Checks: WRITE == 46875 KB exactly; VGPR 40-56.
// Predicted if I$ theory right: 28-36us, VALUBusy 50-65%.
// Falsifier: 48-55us @ ~37% -> I$ theory dead (caveat: s_load prefetch
// shape also changed); next = occupancy forcing vs store coalescing.
// ---------------------------------------------------------------------------

#define K_A   (0.10846522890932808f * 0.24253562503633297f)  // C2_000*C1_000
#define K_B   (0.10846522890932808f * 0.14002800840979312f)  // C2_000*C1_110
#define K_P   (0.06262242910851495f * 0.33333333333333333f)  // C2_110*C1_011
#define K_Q   (0.06262242910851495f * 0.33333333333333333f)  // C2_110*C1_101
#define K_R   (0.06262242910851495f * 0.23570226039551584f)  // C2_110*C1_111
#define K_WB  (0.14907119849998599f * 0.24253562503633297f)  // C2_011*C1_000
#define K_CB  (0.14907119849998599f * 0.14002800840979312f)  // C2_011*C1_110
#define K_WA  (0.14907119849998599f * 0.33333333333333333f)  // C2_101*C1_011
#define K_WBT (0.14907119849998599f * 0.33333333333333333f)  // C2_101*C1_101
#define K_WC  (0.14907119849998599f * 0.23570226039551584f)  // C2_101*C1_111
#define K_WA3 (0.10540925533894598f * 0.33333333333333333f)  // C2_111*C1_011
#define K_WB3 (0.10540925533894598f * 0.33333333333333333f)  // C2_111*C1_101
#define K_WC3 (0.10540925533894598f * 0.23570226039551584f)  // C2_111*C1_111

// ws layout: 80 rows x 9 floats (rows 77..79 zero) = 720, then extras
#define EX_WB   720   // 16
#define EX_CB   736   // 1 (737..739 pad)
#define EX_WA   740   // 16
#define EX_WBT  756   // 16
#define EX_WC   772   // 4
#define EX_WA3  776   // 4
#define EX_WB3  780   // 4
#define EX_WC3  784   // 1
#define N_WS    785

__global__ void fd13_prep(const float* __restrict__ w1_000, const float* __restrict__ w1_110,
                          const float* __restrict__ w1_011, const float* __restrict__ w1_101,
                          const float* __restrict__ w1_111, const float* __restrict__ w2_000,
                          const float* __restrict__ w2_110, const float* __restrict__ w2_011,
                          const float* __restrict__ w2_101, const float* __restrict__ w2_111,
                          float* __restrict__ ws)
{
    int j = blockIdx.x * 256 + threadIdx.x;
    if (j >= N_WS) return;
    float val = 0.f;
    if (j < 720) {
        int r = j / 9, c = j - r * 9;
        if (r < 64) {                       // s1(x)s2(x)s3 rows
            int pq = r >> 2, v = r & 3;
            float a = 0.f;
            for (int u = 0; u < 20; ++u)
                a = fmaf(w1_000[pq * 20 + u], w2_000[u * 36 + v * 9 + c], a);
            val = K_A * a;
        } else if (r < 68) {                // dot12*s3 rows
            int v = r - 64; float a = 0.f;
            for (int u = 0; u < 20; ++u)
                a = fmaf(w1_110[u], w2_000[u * 36 + v * 9 + c], a);
            val = K_B * a;
        } else if (r < 72) {                // d23*s1 rows
            int u = r - 68; float a = 0.f;
            for (int m = 0; m < 5; ++m)
                a = fmaf(w1_011[u * 5 + m], w2_110[m * 9 + c], a);
            val = K_P * a;
        } else if (r < 76) {                // d13*s2 rows
            int u = r - 72; float a = 0.f;
            for (int m = 0; m < 5; ++m)
                a = fmaf(w1_101[u * 5 + m], w2_110[m * 9 + c], a);
            val = K_Q * a;
        } else if (r == 76) {               // dtp row
            float a = 0.f;
            for (int m = 0; m < 5; ++m)
                a = fmaf(w1_111[m], w2_110[m * 9 + c], a);
            val = K_R * a;
        }                                   // rows 77..79: zero
    } else {
        int k = j - 720;
        if (k < 16) {                       // WB[pq]
            float a = 0.f;
            for (int u = 0; u < 20; ++u)
                a = fmaf(w2_011[u], w1_000[k * 20 + u], a);
            val = K_WB * a;
        } else if (k == 16) {               // CB
            float a = 0.f;
            for (int u = 0; u < 20; ++u)
                a = fmaf(w2_011[u], w1_110[u], a);
            val = K_CB * a;
        } else if (k >= 20 && k < 36) {     // WA[u*4+v]
            int u = (k - 20) >> 2, v = (k - 20) & 3;
            float a = 0.f;
            for (int m = 0; m < 5; ++m)
                a = fmaf(w1_011[u * 5 + m], w2_101[m * 4 + v], a);
            val = K_WA * a;
        } else if (k >= 36 && k < 52) {     // WBT[u*4+v]
            int u = (k - 36) >> 2, v = (k - 36) & 3;
            float a = 0.f;
            for (int m = 0; m < 5; ++m)
                a = fmaf(w1_101[u * 5 + m], w2_101[m * 4 + v], a);
            val = K_WBT * a;
        } else if (k >= 52 && k < 56) {     // WC[v]
            int v = k - 52; float a = 0.f;
            for (int m = 0; m < 5; ++m)
                a = fmaf(w1_111[m], w2_101[m * 4 + v], a);
            val = K_WC * a;
        } else if (k >= 56 && k < 60) {     // WA3[u]
            int u = k - 56; float a = 0.f;
            for (int m = 0; m < 5; ++m)
                a = fmaf(w2_111[m], w1_011[u * 5 + m], a);
            val = K_WA3 * a;
        } else if (k >= 60 && k < 64) {     // WB3[v]
            int v = k - 60; float a = 0.f;
            for (int m = 0; m < 5; ++m)
                a = fmaf(w2_111[m], w1_101[v * 5 + m], a);
            val = K_WB3 * a;
        } else if (k == 64) {               // WC3
            float a = 0.f;
            for (int m = 0; m < 5; ++m)
                a = fmaf(w2_111[m], w1_111[m], a);
            val = K_WC3 * a;
        }
    }
    ws[j] = val;
}

__global__ __launch_bounds__(256) void
fd13(const float* __restrict__ lig, const float* __restrict__ rec,
     const float* __restrict__ ws, float* __restrict__ out, int n)
{
    const int tid = blockIdx.x * 256 + threadIdx.x;
    if (tid >= n) return;

    const float4* L = (const float4*)(lig + (size_t)tid * 12);
    const float4* R = (const float4*)(rec + (size_t)tid * 12);
    float4 l0 = L[0], l1 = L[1], l2 = L[2];
    float4 r0 = R[0], r1 = R[1], r2 = R[2];

    float e1x = l0.w - r0.w, e1y = l1.x - r1.x, e1z = l1.y - r1.y;
    float e2x = l1.z - r1.z, e2y = l1.w - r1.w, e2z = l2.x - r2.x;
    float e3x = l2.y - r2.y, e3y = l2.z - r2.z, e3z = l2.w - r2.w;

    float n1 = fmaf(e1x, e1x, fmaf(e1y, e1y, e1z * e1z));
    float n2 = fmaf(e2x, e2x, fmaf(e2y, e2y, e2z * e2z));
    float n3sq = fmaf(e3x, e3x, fmaf(e3y, e3y, e3z * e3z));
    float i1 = __builtin_amdgcn_rsqf(n1);
    float i2 = __builtin_amdgcn_rsqf(n2);
    float i3 = __builtin_amdgcn_rsqf(n3sq);
    float d1 = n1 * i1, d2 = n2 * i2, d3 = n3sq * i3;

    float v1x = e1x * i1, v1y = e1y * i1, v1z = e1z * i1;
    float v2x = e2x * i2, v2y = e2y * i2, v2z = e2z * i2;
    float v3x = e3x * i3, v3y = e3y * i3, v3z = e3z * i3;

    const float coeff = -0.18f;
    const float o1 = 1.6666666f, o2 = 3.3333333f, o3 = 5.f;
    // Named scalars only — no arrays anywhere (scratch rule #20).
    float x;
    float s1v0, s1v1, s1v2, s1v3, s2v0, s2v1, s2v2, s2v3, s3v0, s3v1, s3v2, s3v3;
    x = d1;      s1v0 = __expf(coeff * x * x);
    x = d1 - o1; s1v1 = __expf(coeff * x * x);
    x = d1 - o2; s1v2 = __expf(coeff * x * x);
    x = d1 - o3; s1v3 = __expf(coeff * x * x);
    x = d2;      s2v0 = __expf(coeff * x * x);
    x = d2 - o1; s2v1 = __expf(coeff * x * x);
    x = d2 - o2; s2v2 = __expf(coeff * x * x);
    x = d2 - o3; s2v3 = __expf(coeff * x * x);
    x = d3;      s3v0 = __expf(coeff * x * x);
    x = d3 - o1; s3v1 = __expf(coeff * x * x);
    x = d3 - o2; s3v2 = __expf(coeff * x * x);
    x = d3 - o3; s3v3 = __expf(coeff * x * x);

    float dot12 = v1x * v2x + v1y * v2y + v1z * v2z;
    float d13   = v1x * v3x + v1y * v3y + v1z * v3z;
    float d23   = v2x * v3x + v2y * v3y + v2z * v3z;
    float c12x = v1y * v2z - v1z * v2y;
    float c12y = v1z * v2x - v1x * v2z;
    float c12z = v1x * v2y - v1y * v2x;
    float dtp  = c12x * v3x + c12y * v3y + c12z * v3z;

    // ---------------- 77-row matvec, 9 scalar accumulators ----------------
    float acc0 = 0.f, acc1 = 0.f, acc2 = 0.f, acc3 = 0.f, acc4 = 0.f;
    float acc5 = 0.f, acc6 = 0.f, acc7 = 0.f, acc8 = 0.f;

#define ROW9(off_, x_) do { \
    const float x9_ = (x_); \
    acc0 = fmaf(x9_, wp[(off_) + 0], acc0); acc1 = fmaf(x9_, wp[(off_) + 1], acc1); \
    acc2 = fmaf(x9_, wp[(off_) + 2], acc2); acc3 = fmaf(x9_, wp[(off_) + 3], acc3); \
    acc4 = fmaf(x9_, wp[(off_) + 4], acc4); acc5 = fmaf(x9_, wp[(off_) + 5], acc5); \
    acc6 = fmaf(x9_, wp[(off_) + 6], acc6); acc7 = fmaf(x9_, wp[(off_) + 7], acc7); \
    acc8 = fmaf(x9_, wp[(off_) + 8], acc8); \
} while (0)

    // One q-group: same per-group FMA order as r8 (rows 0..3, cols 0..8).
#define GROUPQ(qi_, s2q_) do { \
    const float o_ = s1p * (s2q_); \
    sg = fmaf(o_, wbp[qi_], sg); \
    const float x0_ = o_ * s3v0, x1_ = o_ * s3v1, x2_ = o_ * s3v2, x3_ = o_ * s3v3; \
    ROW9(36 * (qi_) + 0,  x0_); \
    ROW9(36 * (qi_) + 9,  x1_); \
    ROW9(36 * (qi_) + 18, x2_); \
    ROW9(36 * (qi_) + 27, x3_); \
} while (0)

    float sg = dot12 * ws[EX_CB];

    // p-loop kept rolled (code-size experiment): s1 selection by register
    // rotation (3 v_mov/iter), q fully unrolled inside. Group visit order
    // pq = 0..15 and all chain orders identical to r8 -> bitwise-identical.
    {
        const float* wp  = ws;
        const float* wbp = ws + EX_WB;
        float s1p = s1v0, s1n1 = s1v1, s1n2 = s1v2, s1n3 = s1v3;
#pragma unroll 1
        for (int p = 0; p < 4; ++p) {
            GROUPQ(0, s2v0);
            GROUPQ(1, s2v1);
            GROUPQ(2, s2v2);
            GROUPQ(3, s2v3);
            wp += 144;
            wbp += 4;
            s1p = s1n1; s1n1 = s1n2; s1n2 = s1n3;
        }
    }
#undef GROUPQ

    // Tail groups 16..19: straight-line (r8 layout and order).
#define GROUP4T(g, x0v, x1v, x2v, x3v) do { \
    const float* wp = ws + 36 * (g); \
    ROW9(0,  (x0v)); \
    ROW9(9,  (x1v)); \
    ROW9(18, (x2v)); \
    ROW9(27, (x3v)); \
} while (0)

    GROUP4T(16, dot12 * s3v0, dot12 * s3v1, dot12 * s3v2, dot12 * s3v3);
    GROUP4T(17, d23 * s1v0, d23 * s1v1, d23 * s1v2, d23 * s1v3);
    GROUP4T(18, d13 * s2v0, d13 * s2v1, d13 * s2v2, d13 * s2v3);
    {   // row 76 only (77..79 are zero)
        const float* wp = ws + 36 * 19;
        ROW9(0, dtp);
    }
#undef GROUP4T
#undef ROW9

    // ---------------- epilogue scalars (r8) ----------------
    float ta = 0.f, tb = 0.f;
    {
        float da, db;
        da = fmaf(ws[EX_WA + 0],  s3v0, fmaf(ws[EX_WA + 1],  s3v1,
             fmaf(ws[EX_WA + 2],  s3v2, ws[EX_WA + 3]  * s3v3)));
        db = fmaf(ws[EX_WBT + 0], s3v0, fmaf(ws[EX_WBT + 1], s3v1,
             fmaf(ws[EX_WBT + 2], s3v2, ws[EX_WBT + 3] * s3v3)));
        ta = fmaf(s1v0, da, ta); tb = fmaf(s2v0, db, tb);
        da = fmaf(ws[EX_WA + 4],  s3v0, fmaf(ws[EX_WA + 5],  s3v1,
             fmaf(ws[EX_WA + 6],  s3v2, ws[EX_WA + 7]  * s3v3)));
        db = fmaf(ws[EX_WBT + 4], s3v0, fmaf(ws[EX_WBT + 5], s3v1,
             fmaf(ws[EX_WBT + 6], s3v2, ws[EX_WBT + 7] * s3v3)));
        ta = fmaf(s1v1, da, ta); tb = fmaf(s2v1, db, tb);
        da = fmaf(ws[EX_WA + 8],  s3v0, fmaf(ws[EX_WA + 9],  s3v1,
             fmaf(ws[EX_WA + 10], s3v2, ws[EX_WA + 11] * s3v3)));
        db = fmaf(ws[EX_WBT + 8], s3v0, fmaf(ws[EX_WBT + 9], s3v1,
             fmaf(ws[EX_WBT + 10], s3v2, ws[EX_WBT + 11] * s3v3)));
        ta = fmaf(s1v2, da, ta); tb = fmaf(s2v2, db, tb);
        da = fmaf(ws[EX_WA + 12], s3v0, fmaf(ws[EX_WA + 13], s3v1,
             fmaf(ws[EX_WA + 14], s3v2, ws[EX_WA + 15] * s3v3)));
        db = fmaf(ws[EX_WBT + 12], s3v0, fmaf(ws[EX_WBT + 13], s3v1,
             fmaf(ws[EX_WBT + 14], s3v2, ws[EX_WBT + 15] * s3v3)));
        ta = fmaf(s1v3, da, ta); tb = fmaf(s2v3, db, tb);
    }
    float tc = fmaf(ws[EX_WC + 0], s3v0, fmaf(ws[EX_WC + 1], s3v1,
               fmaf(ws[EX_WC + 2], s3v2, ws[EX_WC + 3] * s3v3)));
    float wa = fmaf(ws[EX_WA3 + 0], s1v0, fmaf(ws[EX_WA3 + 1], s1v1,
               fmaf(ws[EX_WA3 + 2], s1v2, ws[EX_WA3 + 3] * s1v3)));
    float wb = fmaf(ws[EX_WB3 + 0], s2v0, fmaf(ws[EX_WB3 + 1], s2v1,
               fmaf(ws[EX_WB3 + 2], s2v2, ws[EX_WB3 + 3] * s2v3)));
    float wc = ws[EX_WC3];

    float c23x = v2y * v3z - v2z * v3y;
    float c23y = v2z * v3x - v2x * v3z;
    float c23z = v2x * v3y - v2y * v3x;
    float c13x = v1y * v3z - v1z * v3y;
    float c13y = v1z * v3x - v1x * v3z;
    float c13z = v1x * v3y - v1y * v3x;
    float ccrx = c12y * v3z - c12z * v3y;
    float ccry = c12z * v3x - c12x * v3z;
    float ccrz = c12x * v3y - c12y * v3x;

    float V2x = sg * v3x + ta * v2x + tb * v1x + tc * c12x + wa * c23x + wb * c13x + wc * ccrx;
    float V2y = sg * v3y + ta * v2y + tb * v1y + tc * c12y + wa * c23y + wb * c13y + wc * ccry;
    float V2z = sg * v3z + ta * v2z + tb * v1z + tc * c12z + wa * c23z + wb * c13z + wc * ccrz;

    // ---------------- stores (r8 pattern) ----------------
    const size_t n3 = (size_t)n * 3;
    const size_t base = (size_t)tid * 3;
    out[base + 0] = acc0;
    out[base + 1] = acc1;
    out[base + 2] = acc2;
    out[n3 + base + 0] = acc3;
    out[n3 + base + 1] = acc4;
    out[n3 + base + 2] = acc5;
    out[2 * n3 + base + 0] = acc6;
    out[2 * n3 + base + 1] = acc7;
    out[2 * n3 + base + 2] = acc8;
    out[3 * n3 + base + 0] = V2x;
    out[3 * n3 + base + 1] = V2y;
    out[3 * n3 + base + 2] = V2z;
}

extern "C" void kernel_launch(void* const* d_in, const int* in_sizes, int n_in,
                              void* d_out, int out_size, void* d_ws, size_t ws_size,
                              hipStream_t stream) {
    const float* lig = (const float*)d_in[0];
    const float* rec = (const float*)d_in[1];
    float* ws = (float*)d_ws;

    fd13_prep<<<4, 256, 0, stream>>>(
        (const float*)d_in[2], (const float*)d_in[3], (const float*)d_in[4],
        (const float*)d_in[5], (const float*)d_in[6], (const float*)d_in[7],
        (const float*)d_in[8], (const float*)d_in[9], (const float*)d_in[10],
        (const float*)d_in[11], ws);

    int n = in_sizes[0] / 12;
    int blocks = (n + 255) / 256;
    fd13<<<blocks, 256, 0, stream>>>(lig, rec, ws, (float*)d_out, n);
}